// Round 9
// baseline (772.776 us; speedup 1.0000x reference)
//
#include <hip/hip_runtime.h>
#include <hip/hip_bf16.h>

// RecNN: u = relu(contents @ W_u^T + b_u); v = u[internal] @ W_hu^T (hoisted);
// 10 levels emb = relu([emb_L|emb_R] @ W_LR^T + v + b_h).
//
// Round-9: A-IN-LDS-ONCE + B-REGISTER-DIRECT. r1-r8 showed the glds staging
// path saturates ~5 TB/s aggregate no matter the pipelining, and B-tile
// re-staging dominated staged bytes (~2 GB). Weights are L2-resident
// (W_u 256 KB, W_h 1.5 MB), so B fragments now load global->register per
// k-step (16 B/lane, L1/L2 path, ~7+ TB/s measured in r6), while the A tile
// (used once) is staged to LDS a single time per block via plain
// loads+ds_write (fp32 convert fused for GEMM1; per-lane gather for levels).
// Block = 256 thr / 4 waves = one 64-row m-tile x full N=512 (wave owns a
// 128-col slice, acc[4][8]); 1-3 barriers per block TOTAL, waves otherwise
// independent. K chunks of <=512 (levels: L-half then R-half).

typedef unsigned short u16;
typedef __attribute__((ext_vector_type(8))) short bf16x8;
typedef __attribute__((ext_vector_type(4))) float f32x4;

__device__ __forceinline__ u16 f2b(float f) {
  union { float f; unsigned u; } c; c.f = f;
  unsigned u = c.u;
  return (u16)((u + 0x7fffu + ((u >> 16) & 1u)) >> 16);  // RNE
}

__device__ __forceinline__ float b2f(unsigned hi16) {
  union { float f; unsigned u; } c; c.u = hi16 << 16; return c.f;
}

// EPI 0: A fp32 [M][256] (cvt in staging), bias+relu      (GEMM1, K=256)
// EPI 2: A bf16 [M][512] linear, raw store                (v-GEMM, K=512)
// EPI 1: A gathered emb[idx.x]|emb[idx.y], +v+bias+relu   (levels, K=2x512)
// M must be a multiple of 64. Block = 1 m-tile (64 rows) x N=512.
template <int EPI>
__global__ __launch_bounds__(256, 2)
void gemm_aw(const float* __restrict__ Af32,
             const u16* __restrict__ Abf,
             const u16* __restrict__ embPrev,
             const int2* __restrict__ idx,
             const u16* __restrict__ vLvl,   // [M][512] bf16
             const u16* __restrict__ W,      // bf16, row stride ldb (B^T)
             int ldb,
             const float* __restrict__ bias,
             u16* __restrict__ out) {        // [M][512] bf16
  constexpr int CK = (EPI == 0) ? 256 : 512;   // K per chunk
  constexpr int NH = (EPI == 1) ? 2 : 1;       // chunks
  __shared__ __align__(16) u16 lA[64 * CK];    // 32 KB (EPI0) / 64 KB

  const int tid  = threadIdx.x;
  const int lane = tid & 63;
  const int wv   = tid >> 6;          // wave = 128-col n-slice
  const int m0   = blockIdx.x * 64;
  const int n0   = wv * 128;
  const int fm   = lane & 15;
  const int kk   = (lane >> 4) * 8;

  // Staging decode: thread covers row sr, 8-col piece q within each 32-block.
  const int sr = tid >> 2;            // 0..63
  const int sq = tid & 3;

  // B row pointers (8 frag rows: n0 + j*16 + fm), pre-offset by kk.
  const u16* bp[8];
#pragma unroll
  for (int j = 0; j < 8; j++)
    bp[j] = W + (size_t)(n0 + j * 16 + fm) * ldb + kk;

  f32x4 acc[4][8] = {};

  for (int h = 0; h < NH; h++) {
    // ---- stage A chunk into LDS (once per chunk) ----
    if (h) __syncthreads();           // all reads of previous chunk done
    if (EPI == 0) {
      const float* src = Af32 + (size_t)(m0 + sr) * 256;
#pragma unroll
      for (int i = 0; i < CK / 32; i++) {
        int c = sq * 8 + i * 32;
        const float4* s = (const float4*)(src + c);
        float4 a = s[0], b = s[1];
        union { __hip_bfloat162 hh[4]; bf16x8 v; } o;
        o.hh[0] = __float22bfloat162_rn({a.x, a.y});
        o.hh[1] = __float22bfloat162_rn({a.z, a.w});
        o.hh[2] = __float22bfloat162_rn({b.x, b.y});
        o.hh[3] = __float22bfloat162_rn({b.z, b.w});
        *(bf16x8*)&lA[i * 2048 + sr * 32 + sq * 8] = o.v;
      }
    } else {
      const u16* src;
      if (EPI == 2) {
        src = Abf + (size_t)(m0 + sr) * 512;
      } else {
        int2 cc = idx[m0 + sr];
        src = embPrev + (size_t)(h ? cc.y : cc.x) * 512;
      }
#pragma unroll
      for (int i = 0; i < CK / 32; i++) {
        int c = sq * 8 + i * 32;
        *(bf16x8*)&lA[i * 2048 + sr * 32 + sq * 8] = *(const bf16x8*)(src + c);
      }
    }
    __syncthreads();

    // ---- k-steps over this chunk: B reg-direct (1-step prefetch) ----
    const int kb = h ? 512 : 0;       // global k base into W
    bf16x8 bv0[8], bv1[8];
    auto loadB = [&](int k, bf16x8* bb) {
#pragma unroll
      for (int j = 0; j < 8; j++) bb[j] = *(const bf16x8*)(bp[j] + k);
    };
    auto step = [&](int kc, bf16x8* bb) {
      bf16x8 av[4];
#pragma unroll
      for (int i = 0; i < 4; i++)
        av[i] = *(const bf16x8*)&lA[kc * 64 + (i * 16 + fm) * 32 + kk];
#pragma unroll
      for (int i = 0; i < 4; i++)
#pragma unroll
        for (int j = 0; j < 8; j++)
          acc[i][j] = __builtin_amdgcn_mfma_f32_16x16x32_bf16(av[i], bb[j], acc[i][j], 0, 0, 0);
    };

    loadB(kb, bv0);
    for (int kc = 0; kc < CK; kc += 64) {
      if (kc + 32 < CK) loadB(kb + kc + 32, bv1);
      step(kc, bv0);
      if (kc + 64 < CK) loadB(kb + kc + 64, bv0);
      if (kc + 32 < CK) step(kc + 32, bv1);
    }
  }

  // Epilogue: C/D layout col=lane&15, row=(lane>>4)*4+reg (m89-verified).
  const int r0 = (lane >> 4) * 4;
#pragma unroll
  for (int i = 0; i < 4; i++) {
    int mI = m0 + i * 16 + r0;
#pragma unroll
    for (int j = 0; j < 8; j++) {
      int col = n0 + j * 16 + fm;
      float bb = (EPI == 2) ? 0.f : bias[col];
#pragma unroll
      for (int r = 0; r < 4; r++) {
        int m = mI + r;
        float v = acc[i][j][r] + bb;
        if (EPI == 1) v += b2f(vLvl[(size_t)m * 512 + col]);
        if (EPI != 2) v = v > 0.f ? v : 0.f;
        out[(size_t)m * 512 + col] = f2b(v);
      }
    }
  }
}

// One launch: convert W_u (512x256) and W_h (512x1536) fp32 -> bf16.
__global__ void cvt_weights(const float* __restrict__ Wu,
                            const float* __restrict__ Wh,
                            u16* __restrict__ Wub, u16* __restrict__ Whb) {
  const int nWu = 512 * 256 / 8;
  const int nWh = 512 * 1536 / 8;
  int i = blockIdx.x * blockDim.x + threadIdx.x;
  const float* src; u16* dst; int c;
  if (i < nWu) { src = Wu; dst = Wub; c = i; }
  else if (i < nWu + nWh) { src = Wh; dst = Whb; c = i - nWu; }
  else return;
  const float4* s = (const float4*)(src + (size_t)c * 8);
  float4 a = s[0], b = s[1];
  union { __hip_bfloat162 h[4]; bf16x8 v; } o;
  o.h[0] = __float22bfloat162_rn({a.x, a.y});
  o.h[1] = __float22bfloat162_rn({a.z, a.w});
  o.h[2] = __float22bfloat162_rn({b.x, b.y});
  o.h[3] = __float22bfloat162_rn({b.z, b.w});
  *(bf16x8*)(dst + (size_t)c * 8) = o.v;
}

__global__ void cvt_bf16_to_f32(const u16* __restrict__ src, float* __restrict__ dst, int n4) {
  int i = blockIdx.x * blockDim.x + threadIdx.x;
  if (i >= n4) return;
  uint2 p = ((const uint2*)src)[i];
  float4 o;
  o.x = b2f(p.x & 0xffffu); o.y = b2f(p.x >> 16);
  o.z = b2f(p.y & 0xffffu); o.w = b2f(p.y >> 16);
  ((float4*)dst)[i] = o;
}

extern "C" void kernel_launch(void* const* d_in, const int* in_sizes, int n_in,
                              void* d_out, int out_size, void* d_ws, size_t ws_size,
                              hipStream_t stream) {
  const float* contents = (const float*)d_in[0];
  const int2*  children = (const int2*)d_in[1];
  const float* W_u = (const float*)d_in[2];
  const float* b_u = (const float*)d_in[3];
  const float* W_h = (const float*)d_in[4];
  const float* b_h = (const float*)d_in[5];
  float* out = (float*)d_out;

  const int B = 64, D = 11, F = 256, H = 512;
  const int N = B * ((1 << D) - 1);            // 131008
  const int NI = B * ((1 << (D - 1)) - 1);     // 65472

  // Workspace (u16 elems): u_bf [N*512] | v_bf [NI*512] | Wub | Whb.
  // emb ping-pong aliases u's internal rows (dead after the v-GEMM).
  u16* ws16 = (u16*)d_ws;
  u16* u_bf = ws16;
  u16* v_bf = ws16 + (size_t)N * H;
  u16* Wub  = v_bf + (size_t)NI * H;
  u16* Whb  = Wub + 512 * 256;
  u16* embA = u_bf;                            // level-9 dst (32768 rows)
  u16* embB = u_bf + (size_t)32768 * 512;      // internal rows, dead

  // --- weight conversion (single tiny launch) ---
  {
    int n = (512 * 256 + 512 * 1536) / 8;
    cvt_weights<<<(n + 255) / 256, 256, 0, stream>>>(W_u, W_h, Wub, Whb);
  }

  // --- GEMM1: u = relu(contents @ W_u^T + b_u), fp32 A cvt in staging ---
  gemm_aw<0><<<N / 64, 256, 0, stream>>>(contents, nullptr, nullptr, nullptr,
                                         nullptr, Wub, F, b_u, u_bf);

  // --- v-GEMM: v = u[0:NI] @ W_hu^T (W_h cols 1024..1535 in place) ---
  gemm_aw<2><<<NI / 64, 256, 0, stream>>>(nullptr, u_bf, nullptr, nullptr,
                                          nullptr, Whb + 1024, 3 * H,
                                          nullptr, v_bf);

  // --- tree levels j = D-2 .. 0 (K=1024 as L-half then R-half) ---
  const u16* embPrev = u_bf + (size_t)NI * H;  // leaves = u[NI:]
  u16* dst = embA;
  for (int j = D - 2; j >= 0; --j) {
    int M = B << j;
    int o = B * ((1 << j) - 1);
    gemm_aw<1><<<M / 64, 256, 0, stream>>>(nullptr, nullptr, embPrev,
                                           children + o, v_bf + (size_t)o * H,
                                           Whb, 3 * H, b_h, dst);
    embPrev = dst;
    dst = (dst == embA) ? embB : embA;
  }

  // --- level-0 emb (64 x 512) -> fp32 output ---
  {
    int n4 = B * H / 4;
    cvt_bf16_to_f32<<<(n4 + 255) / 256, 256, 0, stream>>>(embPrev, out, n4);
  }
}